// Round 1
// baseline (2437.411 us; speedup 1.0000x reference)
//
#include <hip/hip_runtime.h>
#include <math.h>

#define F_IN 128
#define HID  32

// ---------------- degree / normalization ----------------

__global__ void k_init_deg(float* __restrict__ deg, int n) {
    int i = blockIdx.x * 256 + threadIdx.x;
    if (i < n) deg[i] = 1.0f;   // self-loop
}

__global__ void k_count_deg(const int* __restrict__ dst, float* __restrict__ deg, int e) {
    int i = blockIdx.x * 256 + threadIdx.x;
    if (i < e) unsafeAtomicAdd(&deg[dst[i]], 1.0f);
}

__global__ void k_rsqrt(const float* __restrict__ deg, float* __restrict__ dis, int n) {
    int i = blockIdx.x * 256 + threadIdx.x;
    if (i < n) dis[i] = rsqrtf(deg[i]);
}

// ---------------- transforms ----------------

// u[node][c] = dis[node] * sum_k x[node][k] * W[k][c]   (W: [128,32] row-major)
__global__ __launch_bounds__(256) void k_gemm1(const float* __restrict__ x,
                                               const float* __restrict__ W,
                                               const float* __restrict__ dis,
                                               float* __restrict__ u, int n) {
    __shared__ float Ws[F_IN * HID];   // 16 KB
    __shared__ float xs[8 * F_IN];     // 4 KB
    int tid = threadIdx.x;
    for (int i = tid; i < F_IN * HID; i += 256) Ws[i] = W[i];
    int node0 = blockIdx.x * 8;
    for (int i = tid; i < 8 * F_IN; i += 256) {
        int node = node0 + (i >> 7);
        xs[i] = (node < n) ? x[((size_t)node << 7) + (i & 127)] : 0.0f;
    }
    __syncthreads();
    int g = tid >> 5, c = tid & 31;
    int node = node0 + g;
    float acc = 0.0f;
#pragma unroll 16
    for (int k = 0; k < F_IN; ++k) acc += xs[g * F_IN + k] * Ws[k * HID + c];
    if (node < n) u[(size_t)node * HID + c] = acc * dis[node];
}

// u[node][c] = dis[node] * sum_k h[node][k] * W[k][c]   (W: [32,32])
__global__ __launch_bounds__(256) void k_gemm2(const float* __restrict__ h,
                                               const float* __restrict__ W,
                                               const float* __restrict__ dis,
                                               float* __restrict__ u, int n) {
    __shared__ float Ws[HID * HID];    // 4 KB
    __shared__ float hs[8 * HID];
    int tid = threadIdx.x;
    for (int i = tid; i < HID * HID; i += 256) Ws[i] = W[i];
    int node0 = blockIdx.x * 8;
    {
        int i = tid;  // exactly 256 = 8*32
        int node = node0 + (i >> 5);
        hs[i] = (node < n) ? h[(size_t)node * HID + (i & 31)] : 0.0f;
    }
    __syncthreads();
    int g = tid >> 5, c = tid & 31;
    int node = node0 + g;
    float acc = 0.0f;
#pragma unroll
    for (int k = 0; k < HID; ++k) acc += hs[g * HID + k] * Ws[k * HID + c];
    if (node < n) u[(size_t)node * HID + c] = acc * dis[node];
}

// ---------------- edge scatter ----------------

// acc[dst][:] += u[src][:]   (32 floats per edge, 8 lanes/edge x float4)
__global__ void k_scatter32(const float* __restrict__ u,
                            const int* __restrict__ src, const int* __restrict__ dst,
                            float* __restrict__ acc, int e) {
    long long t = (long long)blockIdx.x * 256 + threadIdx.x;
    if (t >= (long long)e * 8) return;
    int ed = (int)(t >> 3), q = (int)(t & 7);
    int s = src[ed], d = dst[ed];
    float4 v = ((const float4*)u)[(size_t)s * 8 + q];
    float* bp = acc + (size_t)d * HID + q * 4;
    unsafeAtomicAdd(bp + 0, v.x);
    unsafeAtomicAdd(bp + 1, v.y);
    unsafeAtomicAdd(bp + 2, v.z);
    unsafeAtomicAdd(bp + 3, v.w);
}

// acc[dst] += s[src]   (scalar, layer 3)
__global__ void k_scatter1(const float* __restrict__ sv,
                           const int* __restrict__ src, const int* __restrict__ dst,
                           float* __restrict__ acc, int e) {
    int i = blockIdx.x * 256 + threadIdx.x;
    if (i < e) unsafeAtomicAdd(&acc[dst[i]], sv[src[i]]);
}

// ---------------- epilogues ----------------

// h[node][c] = relu(dis[node] * (acc[node][c] + u[node][c]) + b[c]), float4-vectorized
__global__ void k_finish(const float4* __restrict__ u4, const float4* __restrict__ acc4,
                         const float* __restrict__ dis, const float* __restrict__ b,
                         float4* __restrict__ out4, int n) {
    int t = blockIdx.x * 256 + threadIdx.x;
    if (t >= n * 8) return;
    int node = t >> 3, q = t & 7;
    float4 u = u4[t], a = acc4[t];
    float ds = dis[node];
    float4 r;
    r.x = fmaxf(ds * (a.x + u.x) + b[q * 4 + 0], 0.0f);
    r.y = fmaxf(ds * (a.y + u.y) + b[q * 4 + 1], 0.0f);
    r.z = fmaxf(ds * (a.z + u.z) + b[q * 4 + 2], 0.0f);
    r.w = fmaxf(ds * (a.w + u.w) + b[q * 4 + 3], 0.0f);
    out4[t] = r;
}

// s[node] = dis[node] * sum_c h[node][c] * W3[c]
__global__ void k_dot32(const float* __restrict__ h, const float* __restrict__ W3,
                        const float* __restrict__ dis, float* __restrict__ s, int n) {
    int tid = threadIdx.x;
    int c = tid & 31, g = tid >> 5;
    int node = blockIdx.x * 8 + g;
    float v = 0.0f;
    if (node < n) v = h[(size_t)node * HID + c] * W3[c];
#pragma unroll
    for (int off = 16; off > 0; off >>= 1) v += __shfl_down(v, off, 32);
    if (node < n && c == 0) s[node] = v * dis[node];
}

__global__ void k_final(const float* __restrict__ sv, const float* __restrict__ acc,
                        const float* __restrict__ dis, const float* __restrict__ b3,
                        float* __restrict__ out, int n) {
    int i = blockIdx.x * 256 + threadIdx.x;
    if (i < n) {
        float z = dis[i] * (acc[i] + sv[i]) + b3[0];
        out[i] = 1.0f / (1.0f + expf(-z));
    }
}

// ---------------- launch ----------------

extern "C" void kernel_launch(void* const* d_in, const int* in_sizes, int n_in,
                              void* d_out, int out_size, void* d_ws, size_t ws_size,
                              hipStream_t stream) {
    const float* x  = (const float*)d_in[0];
    const int*   ei = (const int*)d_in[1];      // [2, E] int32
    const float* W1 = (const float*)d_in[2];
    const float* b1 = (const float*)d_in[3];
    const float* W2 = (const float*)d_in[4];
    const float* b2 = (const float*)d_in[5];
    const float* W3 = (const float*)d_in[6];
    const float* b3 = (const float*)d_in[7];
    float* out = (float*)d_out;

    int n = out_size;             // 150000
    int e = in_sizes[1] / 2;      // 2400000
    const int* src = ei;
    const int* dst = ei + e;

    // workspace layout (floats): A[n*32] | B[n*32] | dis[n] | C[n] | D[n]
    float* A   = (float*)d_ws;
    float* B   = A + (size_t)n * HID;
    float* dis = B + (size_t)n * HID;
    float* Cs  = dis + n;
    float* Dacc = Cs + n;

    dim3 blk(256);
    int gN  = (n + 255) / 256;
    int gE  = (e + 255) / 256;
    int g8  = (n + 7) / 8;
    int gN8 = (n * 8 + 255) / 256;
    int gE8 = (int)(((long long)e * 8 + 255) / 256);

    // degrees -> dis
    k_init_deg<<<gN, blk, 0, stream>>>(Dacc, n);
    k_count_deg<<<gE, blk, 0, stream>>>(dst, Dacc, e);
    k_rsqrt<<<gN, blk, 0, stream>>>(Dacc, dis, n);

    // layer 1: u1 = (x@W1)*dis -> A ; B = scatter(A) ; h1 = relu(dis*(B+A)+b1) -> A
    k_gemm1<<<g8, blk, 0, stream>>>(x, W1, dis, A, n);
    hipMemsetAsync(B, 0, (size_t)n * HID * sizeof(float), stream);
    k_scatter32<<<gE8, blk, 0, stream>>>(A, src, dst, B, e);
    k_finish<<<gN8, blk, 0, stream>>>((const float4*)A, (const float4*)B, dis, b1,
                                      (float4*)A, n);

    // layer 2: u2 = (h1@W2)*dis -> B ; A = scatter(B) ; h2 = relu(dis*(A+B)+b2) -> B
    k_gemm2<<<g8, blk, 0, stream>>>(A, W2, dis, B, n);
    hipMemsetAsync(A, 0, (size_t)n * HID * sizeof(float), stream);
    k_scatter32<<<gE8, blk, 0, stream>>>(B, src, dst, A, e);
    k_finish<<<gN8, blk, 0, stream>>>((const float4*)B, (const float4*)A, dis, b2,
                                      (float4*)B, n);

    // layer 3: s = dis*(h2@W3) -> C ; D = scatter(C) ; out = sigmoid(dis*(D+C)+b3)
    k_dot32<<<g8, blk, 0, stream>>>(B, W3, dis, Cs, n);
    hipMemsetAsync(Dacc, 0, (size_t)n * sizeof(float), stream);
    k_scatter1<<<gE, blk, 0, stream>>>(Cs, src, dst, Dacc, e);
    k_final<<<gN, blk, 0, stream>>>(Cs, Dacc, dis, b3, out, n);
}

// Round 2
// 661.350 us; speedup vs baseline: 3.6855x; 3.6855x over previous
//
#include <hip/hip_runtime.h>
#include <math.h>

#define F_IN 128
#define HID  32

// ================= CSR build =================

__global__ void k_hist(const int* __restrict__ dst, int* __restrict__ counts, int e) {
    int i = blockIdx.x * 256 + threadIdx.x;
    if (i < e) atomicAdd(&counts[dst[i]], 1);
}

// phase A: per-block (1024 elems) sums
__global__ void k_scan_a(const int* __restrict__ counts, int* __restrict__ partials, int n) {
    __shared__ int sh[256];
    int b = blockIdx.x, t = threadIdx.x, base = b * 1024;
    int s = 0;
    for (int i = t; i < 1024; i += 256) {
        int idx = base + i;
        s += (idx < n) ? counts[idx] : 0;
    }
    sh[t] = s; __syncthreads();
    for (int off = 128; off > 0; off >>= 1) {
        if (t < off) sh[t] += sh[t + off];
        __syncthreads();
    }
    if (t == 0) partials[b] = sh[0];
}

// phase B: exclusive scan of partials (single thread; nb ~147), also offsets[n]=total
__global__ void k_scan_b(int* __restrict__ partials, int nb, int* __restrict__ offsets, int n) {
    if (blockIdx.x == 0 && threadIdx.x == 0) {
        int acc = 0;
        for (int i = 0; i < nb; ++i) { int v = partials[i]; partials[i] = acc; acc += v; }
        offsets[n] = acc;
    }
}

// phase C: local exclusive scan + base; writes offsets, cursor, dis (=rsqrt(count+1))
__global__ void k_scan_c(const int* __restrict__ counts, const int* __restrict__ partials,
                         int* __restrict__ offsets, int* __restrict__ cursor,
                         float* __restrict__ dis, int n) {
    __shared__ int sh[256];
    int b = blockIdx.x, t = threadIdx.x;
    int base = b * 1024 + t * 4;
    int v[4]; int s = 0;
#pragma unroll
    for (int j = 0; j < 4; ++j) {
        int idx = base + j;
        v[j] = (idx < n) ? counts[idx] : 0;
        s += v[j];
    }
    sh[t] = s; __syncthreads();
    int acc = s;
    for (int off = 1; off < 256; off <<= 1) {
        int add = (t >= off) ? sh[t - off] : 0;
        __syncthreads();
        acc += add;
        sh[t] = acc;
        __syncthreads();
    }
    int running = partials[b] + (acc - s);   // exclusive prefix for this thread
#pragma unroll
    for (int j = 0; j < 4; ++j) {
        int idx = base + j;
        if (idx < n) {
            offsets[idx] = running;
            cursor[idx]  = running;
            dis[idx]     = rsqrtf((float)(v[j] + 1));   // +1 self-loop
        }
        running += v[j];
    }
}

__global__ void k_bucket(const int* __restrict__ src, const int* __restrict__ dst,
                         int* __restrict__ cursor, int* __restrict__ es, int e) {
    int i = blockIdx.x * 256 + threadIdx.x;
    if (i < e) {
        int d = dst[i];
        int pos = atomicAdd(&cursor[d], 1);
        es[pos] = src[i];
    }
}

// ================= transforms =================

// u[node][c] = dis[node] * sum_k x[node][k] * W[k][c]   (W: [128,32] row-major)
__global__ __launch_bounds__(256) void k_gemm1(const float* __restrict__ x,
                                               const float* __restrict__ W,
                                               const float* __restrict__ dis,
                                               float* __restrict__ u, int n) {
    __shared__ float Ws[F_IN * HID];   // 16 KB
    __shared__ float xs[8 * F_IN];     // 4 KB
    int tid = threadIdx.x;
    for (int i = tid; i < F_IN * HID; i += 256) Ws[i] = W[i];
    int node0 = blockIdx.x * 8;
    for (int i = tid; i < 8 * F_IN; i += 256) {
        int node = node0 + (i >> 7);
        xs[i] = (node < n) ? x[((size_t)node << 7) + (i & 127)] : 0.0f;
    }
    __syncthreads();
    int g = tid >> 5, c = tid & 31;
    int node = node0 + g;
    float acc = 0.0f;
#pragma unroll 16
    for (int k = 0; k < F_IN; ++k) acc += xs[g * F_IN + k] * Ws[k * HID + c];
    if (node < n) u[(size_t)node * HID + c] = acc * dis[node];
}

// u[node][c] = dis[node] * sum_k h[node][k] * W[k][c]   (W: [32,32])
__global__ __launch_bounds__(256) void k_gemm2(const float* __restrict__ h,
                                               const float* __restrict__ W,
                                               const float* __restrict__ dis,
                                               float* __restrict__ u, int n) {
    __shared__ float Ws[HID * HID];
    __shared__ float hs[8 * HID];
    int tid = threadIdx.x;
    for (int i = tid; i < HID * HID; i += 256) Ws[i] = W[i];
    int node0 = blockIdx.x * 8;
    {
        int i = tid;
        int node = node0 + (i >> 5);
        hs[i] = (node < n) ? h[(size_t)node * HID + (i & 31)] : 0.0f;
    }
    __syncthreads();
    int g = tid >> 5, c = tid & 31;
    int node = node0 + g;
    float acc = 0.0f;
#pragma unroll
    for (int k = 0; k < HID; ++k) acc += hs[g * HID + k] * Ws[k * HID + c];
    if (node < n) u[(size_t)node * HID + c] = acc * dis[node];
}

// s[node] = dis[node] * sum_c h[node][c] * W3[c]
__global__ void k_dot32(const float* __restrict__ h, const float* __restrict__ W3,
                        const float* __restrict__ dis, float* __restrict__ s, int n) {
    int tid = threadIdx.x;
    int c = tid & 31, g = tid >> 5;
    int node = blockIdx.x * 8 + g;
    float v = 0.0f;
    if (node < n) v = h[(size_t)node * HID + c] * W3[c];
#pragma unroll
    for (int off = 16; off > 0; off >>= 1) v += __shfl_down(v, off, 32);
    if (node < n && c == 0) s[node] = v * dis[node];
}

// ================= gather aggregation (fused epilogue) =================

// h[d][:] = relu(dis[d] * (u[d][:] + sum_{s in N(d)} u[s][:]) + b[:])
// 8 lanes per node, float4 per lane.
__global__ __launch_bounds__(256) void k_gather32(const float4* __restrict__ u4,
                                                  const int* __restrict__ es,
                                                  const int* __restrict__ offsets,
                                                  const float* __restrict__ dis,
                                                  const float* __restrict__ b,
                                                  float4* __restrict__ h4, int n) {
    int t = blockIdx.x * 256 + threadIdx.x;
    int node = t >> 3, q = t & 7;
    if (node >= n) return;
    int s0 = offsets[node];
    int s1 = offsets[node + 1];
    float4 acc = u4[(size_t)node * 8 + q];     // self-loop term
    for (int ei = s0; ei < s1; ++ei) {
        int s = es[ei];
        float4 v = u4[(size_t)s * 8 + q];
        acc.x += v.x; acc.y += v.y; acc.z += v.z; acc.w += v.w;
    }
    float ds = dis[node];
    float4 r;
    r.x = fmaxf(fmaf(ds, acc.x, b[q * 4 + 0]), 0.0f);
    r.y = fmaxf(fmaf(ds, acc.y, b[q * 4 + 1]), 0.0f);
    r.z = fmaxf(fmaf(ds, acc.z, b[q * 4 + 2]), 0.0f);
    r.w = fmaxf(fmaf(ds, acc.w, b[q * 4 + 3]), 0.0f);
    h4[(size_t)node * 8 + q] = r;
}

// out[d] = sigmoid(dis[d] * (s[d] + sum s[src]) + b3)
__global__ void k_gather1(const float* __restrict__ sv, const int* __restrict__ es,
                          const int* __restrict__ offsets, const float* __restrict__ dis,
                          const float* __restrict__ b3, float* __restrict__ out, int n) {
    int d = blockIdx.x * 256 + threadIdx.x;
    if (d >= n) return;
    float acc = sv[d];
    int s0 = offsets[d], s1 = offsets[d + 1];
    for (int ei = s0; ei < s1; ++ei) acc += sv[es[ei]];
    float z = dis[d] * acc + b3[0];
    out[d] = 1.0f / (1.0f + expf(-z));
}

// ================= launch =================

extern "C" void kernel_launch(void* const* d_in, const int* in_sizes, int n_in,
                              void* d_out, int out_size, void* d_ws, size_t ws_size,
                              hipStream_t stream) {
    const float* x  = (const float*)d_in[0];
    const int*   ei = (const int*)d_in[1];
    const float* W1 = (const float*)d_in[2];
    const float* b1 = (const float*)d_in[3];
    const float* W2 = (const float*)d_in[4];
    const float* b2 = (const float*)d_in[5];
    const float* W3 = (const float*)d_in[6];
    const float* b3 = (const float*)d_in[7];
    float* out = (float*)d_out;

    int n = out_size;             // 150000
    int e = in_sizes[1] / 2;      // 2400000
    const int* src = ei;
    const int* dst = ei + e;

    // workspace layout
    float* A       = (float*)d_ws;                     // n*32 f
    float* B       = A + (size_t)n * HID;              // n*32 f
    float* dis     = B + (size_t)n * HID;              // n f
    float* Cs      = dis + n;                          // n f
    int*   counts  = (int*)(Cs + n);                   // n i
    int*   offsets = counts + n;                       // (n+1) i
    int*   cursor  = offsets + (n + 1);                // n i
    int*   es      = cursor + n;                       // e i
    int*   partials= es + e;                           // ~nb i

    dim3 blk(256);
    int gN  = (n + 255) / 256;
    int gE  = (e + 255) / 256;
    int g8  = (n + 7) / 8;
    int gN8 = (n * 8 + 255) / 256;
    int nb  = (n + 1023) / 1024;

    // ---- CSR build + degrees ----
    hipMemsetAsync(counts, 0, (size_t)n * sizeof(int), stream);
    k_hist  <<<gE, blk, 0, stream>>>(dst, counts, e);
    k_scan_a<<<nb, blk, 0, stream>>>(counts, partials, n);
    k_scan_b<<<1, 64, 0, stream>>>(partials, nb, offsets, n);
    k_scan_c<<<nb, blk, 0, stream>>>(counts, partials, offsets, cursor, dis, n);
    k_bucket<<<gE, blk, 0, stream>>>(src, dst, cursor, es, e);

    // ---- layer 1 ----
    k_gemm1   <<<g8,  blk, 0, stream>>>(x, W1, dis, A, n);
    k_gather32<<<gN8, blk, 0, stream>>>((const float4*)A, es, offsets, dis, b1, (float4*)B, n);

    // ---- layer 2 ----
    k_gemm2   <<<g8,  blk, 0, stream>>>(B, W2, dis, A, n);
    k_gather32<<<gN8, blk, 0, stream>>>((const float4*)A, es, offsets, dis, b2, (float4*)B, n);

    // ---- layer 3 ----
    k_dot32  <<<g8, blk, 0, stream>>>(B, W3, dis, Cs, n);
    k_gather1<<<gN, blk, 0, stream>>>(Cs, es, offsets, dis, b3, out, n);
}

// Round 3
// 459.629 us; speedup vs baseline: 5.3030x; 1.4389x over previous
//
#include <hip/hip_runtime.h>
#include <math.h>

#define F_IN 128
#define HID  32

#define NPB   256      // nodes per bucket (dst >> 8)
#define MAXNB 1024     // max buckets supported by the one-block scan
#define EPB   8192     // edges per block in coarse passes

// ================= binned CSR build =================

// P1: coarse histogram of dst>>8 via LDS
__global__ __launch_bounds__(256) void k_bhist(const int* __restrict__ dst,
                                               int* __restrict__ bin_hist,
                                               int e, int nbuckets) {
    __shared__ int h[MAXNB];
    int tid = threadIdx.x;
    for (int i = tid; i < nbuckets; i += 256) h[i] = 0;
    __syncthreads();
    int base = blockIdx.x * EPB;
    int end = base + EPB; if (end > e) end = e;
    for (int i = base + tid; i < end; i += 256)
        atomicAdd(&h[dst[i] >> 8], 1);
    __syncthreads();
    for (int i = tid; i < nbuckets; i += 256)
        if (h[i]) atomicAdd(&bin_hist[i], h[i]);
}

// P2: exclusive scan of bucket counts (single block, 1024 threads)
__global__ __launch_bounds__(1024) void k_bscan(const int* __restrict__ bin_hist,
                                                int* __restrict__ bin_off,
                                                int* __restrict__ bin_cur,
                                                int* __restrict__ offsets,
                                                int nbuckets, int n, int e) {
    __shared__ int sh[MAXNB];
    int t = threadIdx.x;
    int v = (t < nbuckets) ? bin_hist[t] : 0;
    sh[t] = v; __syncthreads();
    for (int off = 1; off < MAXNB; off <<= 1) {
        int a = (t >= off) ? sh[t - off] : 0;
        __syncthreads();
        sh[t] += a;
        __syncthreads();
    }
    int excl = sh[t] - v;
    if (t < nbuckets) { bin_off[t] = excl; bin_cur[t] = excl; }
    if (t == 0) { bin_off[nbuckets] = e; offsets[n] = e; }
}

// P3: partition edges into bucket regions; pack src(18b) | dst_local(8b)<<18
__global__ __launch_bounds__(256) void k_bpart(const int* __restrict__ src,
                                               const int* __restrict__ dst,
                                               int* __restrict__ bin_cur,
                                               unsigned* __restrict__ tmp,
                                               int e, int nbuckets) {
    __shared__ int h[MAXNB];
    __shared__ int lc[MAXNB];
    int tid = threadIdx.x;
    for (int i = tid; i < nbuckets; i += 256) h[i] = 0;
    __syncthreads();
    int base = blockIdx.x * EPB;
    int end = base + EPB; if (end > e) end = e;
    for (int i = base + tid; i < end; i += 256)
        atomicAdd(&h[dst[i] >> 8], 1);
    __syncthreads();
    for (int i = tid; i < nbuckets; i += 256) {
        int c = h[i];
        h[i] = c ? atomicAdd(&bin_cur[i], c) : 0;
        lc[i] = 0;
    }
    __syncthreads();
    for (int i = base + tid; i < end; i += 256) {
        int d = dst[i];
        int b = d >> 8;
        int r = atomicAdd(&lc[b], 1);
        tmp[h[b] + r] = (unsigned)src[i] | ((unsigned)(d & (NPB - 1)) << 18);
    }
}

// P4: per-bucket local CSR: count -> scan -> scatter; emit offsets & dis
__global__ __launch_bounds__(256) void k_bcsr(const unsigned* __restrict__ tmp,
                                              const int* __restrict__ bin_off,
                                              int* __restrict__ es,
                                              int* __restrict__ offsets,
                                              float* __restrict__ dis, int n) {
    __shared__ int cnt[NPB];
    __shared__ int sh[NPB];
    __shared__ int cur[NPB];
    int b = blockIdx.x, t = threadIdx.x;
    cnt[t] = 0;
    __syncthreads();
    int s0 = bin_off[b], s1 = bin_off[b + 1];
    for (int i = s0 + t; i < s1; i += 256)
        atomicAdd(&cnt[(tmp[i] >> 18) & (NPB - 1)], 1);
    __syncthreads();
    int v = cnt[t];
    sh[t] = v; __syncthreads();
    for (int off = 1; off < NPB; off <<= 1) {
        int a = (t >= off) ? sh[t - off] : 0;
        __syncthreads();
        sh[t] += a;
        __syncthreads();
    }
    int excl = sh[t] - v;
    int node = b * NPB + t;
    if (node < n) {
        offsets[node] = s0 + excl;
        dis[node] = rsqrtf((float)(v + 1));   // +1 self-loop
    }
    cur[t] = excl;
    __syncthreads();
    for (int i = s0 + t; i < s1; i += 256) {
        unsigned w = tmp[i];
        int dl = (w >> 18) & (NPB - 1);
        int r = atomicAdd(&cur[dl], 1);
        es[s0 + r] = (int)(w & 0x3FFFFu);
    }
}

// ================= transforms =================

__global__ __launch_bounds__(256) void k_gemm1(const float* __restrict__ x,
                                               const float* __restrict__ W,
                                               const float* __restrict__ dis,
                                               float* __restrict__ u, int n) {
    __shared__ float Ws[F_IN * HID];
    __shared__ float xs[8 * F_IN];
    int tid = threadIdx.x;
    for (int i = tid; i < F_IN * HID; i += 256) Ws[i] = W[i];
    int node0 = blockIdx.x * 8;
    for (int i = tid; i < 8 * F_IN; i += 256) {
        int node = node0 + (i >> 7);
        xs[i] = (node < n) ? x[((size_t)node << 7) + (i & 127)] : 0.0f;
    }
    __syncthreads();
    int g = tid >> 5, c = tid & 31;
    int node = node0 + g;
    float acc = 0.0f;
#pragma unroll 16
    for (int k = 0; k < F_IN; ++k) acc += xs[g * F_IN + k] * Ws[k * HID + c];
    if (node < n) u[(size_t)node * HID + c] = acc * dis[node];
}

__global__ __launch_bounds__(256) void k_gemm2(const float* __restrict__ h,
                                               const float* __restrict__ W,
                                               const float* __restrict__ dis,
                                               float* __restrict__ u, int n) {
    __shared__ float Ws[HID * HID];
    __shared__ float hs[8 * HID];
    int tid = threadIdx.x;
    for (int i = tid; i < HID * HID; i += 256) Ws[i] = W[i];
    int node0 = blockIdx.x * 8;
    {
        int i = tid;
        int node = node0 + (i >> 5);
        hs[i] = (node < n) ? h[(size_t)node * HID + (i & 31)] : 0.0f;
    }
    __syncthreads();
    int g = tid >> 5, c = tid & 31;
    int node = node0 + g;
    float acc = 0.0f;
#pragma unroll
    for (int k = 0; k < HID; ++k) acc += hs[g * HID + k] * Ws[k * HID + c];
    if (node < n) u[(size_t)node * HID + c] = acc * dis[node];
}

__global__ void k_dot32(const float* __restrict__ h, const float* __restrict__ W3,
                        const float* __restrict__ dis, float* __restrict__ s, int n) {
    int tid = threadIdx.x;
    int c = tid & 31, g = tid >> 5;
    int node = blockIdx.x * 8 + g;
    float v = 0.0f;
    if (node < n) v = h[(size_t)node * HID + c] * W3[c];
#pragma unroll
    for (int off = 16; off > 0; off >>= 1) v += __shfl_down(v, off, 32);
    if (node < n && c == 0) s[node] = v * dis[node];
}

// ================= gather aggregation =================

__global__ __launch_bounds__(256) void k_gather32(const float4* __restrict__ u4,
                                                  const int* __restrict__ es,
                                                  const int* __restrict__ offsets,
                                                  const float* __restrict__ dis,
                                                  const float* __restrict__ b,
                                                  float4* __restrict__ h4, int n) {
    int t = blockIdx.x * 256 + threadIdx.x;
    int node = t >> 3, q = t & 7;
    if (node >= n) return;
    int s0 = offsets[node];
    int s1 = offsets[node + 1];
    float4 acc = u4[(size_t)node * 8 + q];
    for (int ei = s0; ei < s1; ++ei) {
        int s = es[ei];
        float4 v = u4[(size_t)s * 8 + q];
        acc.x += v.x; acc.y += v.y; acc.z += v.z; acc.w += v.w;
    }
    float ds = dis[node];
    float4 r;
    r.x = fmaxf(fmaf(ds, acc.x, b[q * 4 + 0]), 0.0f);
    r.y = fmaxf(fmaf(ds, acc.y, b[q * 4 + 1]), 0.0f);
    r.z = fmaxf(fmaf(ds, acc.z, b[q * 4 + 2]), 0.0f);
    r.w = fmaxf(fmaf(ds, acc.w, b[q * 4 + 3]), 0.0f);
    h4[(size_t)node * 8 + q] = r;
}

__global__ void k_gather1(const float* __restrict__ sv, const int* __restrict__ es,
                          const int* __restrict__ offsets, const float* __restrict__ dis,
                          const float* __restrict__ b3, float* __restrict__ out, int n) {
    int d = blockIdx.x * 256 + threadIdx.x;
    if (d >= n) return;
    float acc = sv[d];
    int s0 = offsets[d], s1 = offsets[d + 1];
    for (int ei = s0; ei < s1; ++ei) acc += sv[es[ei]];
    float z = dis[d] * acc + b3[0];
    out[d] = 1.0f / (1.0f + expf(-z));
}

// ================= launch =================

extern "C" void kernel_launch(void* const* d_in, const int* in_sizes, int n_in,
                              void* d_out, int out_size, void* d_ws, size_t ws_size,
                              hipStream_t stream) {
    const float* x  = (const float*)d_in[0];
    const int*   ei = (const int*)d_in[1];
    const float* W1 = (const float*)d_in[2];
    const float* b1 = (const float*)d_in[3];
    const float* W2 = (const float*)d_in[4];
    const float* b2 = (const float*)d_in[5];
    const float* W3 = (const float*)d_in[6];
    const float* b3 = (const float*)d_in[7];
    float* out = (float*)d_out;

    int n = out_size;             // 150000
    int e = in_sizes[1] / 2;      // 2400000
    const int* src = ei;
    const int* dst = ei + e;

    int nbuckets = (n + NPB - 1) / NPB;   // 586

    // workspace layout
    float* A        = (float*)d_ws;                 // n*32 f
    float* B        = A + (size_t)n * HID;          // n*32 f  (also aliases tmp during CSR build)
    float* dis      = B + (size_t)n * HID;          // n f
    float* Cs       = dis + n;                      // n f
    int*   offsets  = (int*)(Cs + n);               // n+1 i
    int*   es       = offsets + (n + 1);            // e i
    int*   bin_hist = es + e;                       // nbuckets i
    int*   bin_off  = bin_hist + nbuckets;          // nbuckets+1 i
    int*   bin_cur  = bin_off + (nbuckets + 1);     // nbuckets i
    unsigned* tmp   = (unsigned*)B;                 // e u32, dead before layer-1 gather writes B

    dim3 blk(256);
    int gN   = (n + 255) / 256;
    int g8   = (n + 7) / 8;
    int gN8  = (n * 8 + 255) / 256;
    int gEb  = (e + EPB - 1) / EPB;   // 293

    // ---- CSR build ----
    hipMemsetAsync(bin_hist, 0, (size_t)nbuckets * sizeof(int), stream);
    k_bhist<<<gEb, blk, 0, stream>>>(dst, bin_hist, e, nbuckets);
    k_bscan<<<1, 1024, 0, stream>>>(bin_hist, bin_off, bin_cur, offsets, nbuckets, n, e);
    k_bpart<<<gEb, blk, 0, stream>>>(src, dst, bin_cur, tmp, e, nbuckets);
    k_bcsr <<<nbuckets, blk, 0, stream>>>(tmp, bin_off, es, offsets, dis, n);

    // ---- layer 1 ----
    k_gemm1   <<<g8,  blk, 0, stream>>>(x, W1, dis, A, n);
    k_gather32<<<gN8, blk, 0, stream>>>((const float4*)A, es, offsets, dis, b1, (float4*)B, n);

    // ---- layer 2 ----
    k_gemm2   <<<g8,  blk, 0, stream>>>(B, W2, dis, A, n);
    k_gather32<<<gN8, blk, 0, stream>>>((const float4*)A, es, offsets, dis, b2, (float4*)B, n);

    // ---- layer 3 ----
    k_dot32  <<<g8, blk, 0, stream>>>(B, W3, dis, Cs, n);
    k_gather1<<<gN, blk, 0, stream>>>(Cs, es, offsets, dis, b3, out, n);
}

// Round 4
// 406.622 us; speedup vs baseline: 5.9943x; 1.1304x over previous
//
#include <hip/hip_runtime.h>
#include <math.h>

#define F_IN 128
#define HID  32

#define NPB   256      // nodes per bucket (dst >> 8)
#define MAXNB 1024     // max buckets supported by the one-block scan
#define EPB   8192     // edges per block in coarse passes

__device__ __forceinline__ void fma4(float4& a, float s, const float4& w) {
    a.x = fmaf(s, w.x, a.x);
    a.y = fmaf(s, w.y, a.y);
    a.z = fmaf(s, w.z, a.z);
    a.w = fmaf(s, w.w, a.w);
}

// ================= binned CSR build =================

__global__ __launch_bounds__(256) void k_bhist(const int* __restrict__ dst,
                                               int* __restrict__ bin_hist,
                                               int e, int nbuckets) {
    __shared__ int h[MAXNB];
    int tid = threadIdx.x;
    for (int i = tid; i < nbuckets; i += 256) h[i] = 0;
    __syncthreads();
    int base = blockIdx.x * EPB;
    int end = base + EPB; if (end > e) end = e;
    for (int i = base + tid; i < end; i += 256)
        atomicAdd(&h[dst[i] >> 8], 1);
    __syncthreads();
    for (int i = tid; i < nbuckets; i += 256)
        if (h[i]) atomicAdd(&bin_hist[i], h[i]);
}

__global__ __launch_bounds__(1024) void k_bscan(const int* __restrict__ bin_hist,
                                                int* __restrict__ bin_off,
                                                int* __restrict__ bin_cur,
                                                int* __restrict__ offsets,
                                                int nbuckets, int n, int e) {
    __shared__ int sh[MAXNB];
    int t = threadIdx.x;
    int v = (t < nbuckets) ? bin_hist[t] : 0;
    sh[t] = v; __syncthreads();
    for (int off = 1; off < MAXNB; off <<= 1) {
        int a = (t >= off) ? sh[t - off] : 0;
        __syncthreads();
        sh[t] += a;
        __syncthreads();
    }
    int excl = sh[t] - v;
    if (t < nbuckets) { bin_off[t] = excl; bin_cur[t] = excl; }
    if (t == 0) { bin_off[nbuckets] = e; offsets[n] = e; }
}

__global__ __launch_bounds__(256) void k_bpart(const int* __restrict__ src,
                                               const int* __restrict__ dst,
                                               int* __restrict__ bin_cur,
                                               unsigned* __restrict__ tmp,
                                               int e, int nbuckets) {
    __shared__ int h[MAXNB];
    __shared__ int lc[MAXNB];
    int tid = threadIdx.x;
    for (int i = tid; i < nbuckets; i += 256) h[i] = 0;
    __syncthreads();
    int base = blockIdx.x * EPB;
    int end = base + EPB; if (end > e) end = e;
    for (int i = base + tid; i < end; i += 256)
        atomicAdd(&h[dst[i] >> 8], 1);
    __syncthreads();
    for (int i = tid; i < nbuckets; i += 256) {
        int c = h[i];
        h[i] = c ? atomicAdd(&bin_cur[i], c) : 0;
        lc[i] = 0;
    }
    __syncthreads();
    for (int i = base + tid; i < end; i += 256) {
        int d = dst[i];
        int b = d >> 8;
        int r = atomicAdd(&lc[b], 1);
        tmp[h[b] + r] = (unsigned)src[i] | ((unsigned)(d & (NPB - 1)) << 18);
    }
}

__global__ __launch_bounds__(256) void k_bcsr(const unsigned* __restrict__ tmp,
                                              const int* __restrict__ bin_off,
                                              int* __restrict__ es,
                                              int* __restrict__ offsets,
                                              float* __restrict__ dis, int n) {
    __shared__ int cnt[NPB];
    __shared__ int sh[NPB];
    __shared__ int cur[NPB];
    int b = blockIdx.x, t = threadIdx.x;
    cnt[t] = 0;
    __syncthreads();
    int s0 = bin_off[b], s1 = bin_off[b + 1];
    for (int i = s0 + t; i < s1; i += 256)
        atomicAdd(&cnt[(tmp[i] >> 18) & (NPB - 1)], 1);
    __syncthreads();
    int v = cnt[t];
    sh[t] = v; __syncthreads();
    for (int off = 1; off < NPB; off <<= 1) {
        int a = (t >= off) ? sh[t - off] : 0;
        __syncthreads();
        sh[t] += a;
        __syncthreads();
    }
    int excl = sh[t] - v;
    int node = b * NPB + t;
    if (node < n) {
        offsets[node] = s0 + excl;
        dis[node] = rsqrtf((float)(v + 1));
    }
    cur[t] = excl;
    __syncthreads();
    for (int i = s0 + t; i < s1; i += 256) {
        unsigned w = tmp[i];
        int dl = (w >> 18) & (NPB - 1);
        int r = atomicAdd(&cur[dl], 1);
        es[s0 + r] = (int)(w & 0x3FFFFu);
    }
}

// ================= transforms =================

// 128 nodes/block; thread = 4 nodes (stride 32) x 4 cols; b128 LDS reads.
__global__ __launch_bounds__(256) void k_gemm1(const float* __restrict__ x,
                                               const float* __restrict__ W,
                                               const float* __restrict__ dis,
                                               float* __restrict__ u, int n) {
    __shared__ float Ws[F_IN * HID];   // 16 KB
    __shared__ float xs[128 * 68];     // 34.8 KB, pitch 68 (K-half staging)
    int tid = threadIdx.x;
    for (int i = tid; i < F_IN * HID; i += 256) Ws[i] = W[i];
    int node0 = blockIdx.x * 128;
    int cg = tid & 7, gq = tid >> 3;
    float4 acc[4];
#pragma unroll
    for (int m = 0; m < 4; ++m) acc[m] = make_float4(0.f, 0.f, 0.f, 0.f);
    const float4* x4g = (const float4*)x;
#pragma unroll
    for (int half = 0; half < 2; ++half) {
        __syncthreads();
        for (int i = tid; i < 128 * 16; i += 256) {
            int row = i >> 4, q = i & 15;
            int node = node0 + row;
            float4 v = (node < n) ? x4g[(size_t)node * 32 + half * 16 + q]
                                  : make_float4(0.f, 0.f, 0.f, 0.f);
            *(float4*)&xs[row * 68 + q * 4] = v;
        }
        __syncthreads();
#pragma unroll 4
        for (int ks = 0; ks < 16; ++ks) {
            int kg = half * 64 + ks * 4;
            float4 w0 = *(const float4*)&Ws[(kg + 0) * HID + cg * 4];
            float4 w1 = *(const float4*)&Ws[(kg + 1) * HID + cg * 4];
            float4 w2 = *(const float4*)&Ws[(kg + 2) * HID + cg * 4];
            float4 w3 = *(const float4*)&Ws[(kg + 3) * HID + cg * 4];
#pragma unroll
            for (int m = 0; m < 4; ++m) {
                float4 xv = *(const float4*)&xs[(gq + 32 * m) * 68 + ks * 4];
                fma4(acc[m], xv.x, w0);
                fma4(acc[m], xv.y, w1);
                fma4(acc[m], xv.z, w2);
                fma4(acc[m], xv.w, w3);
            }
        }
    }
#pragma unroll
    for (int m = 0; m < 4; ++m) {
        int node = node0 + gq + 32 * m;
        if (node < n) {
            float ds = dis[node];
            float4 r;
            r.x = acc[m].x * ds; r.y = acc[m].y * ds;
            r.z = acc[m].z * ds; r.w = acc[m].w * ds;
            *(float4*)&u[(size_t)node * HID + cg * 4] = r;
        }
    }
}

// K=32 variant: 128 nodes/block, same register tiling.
__global__ __launch_bounds__(256) void k_gemm2(const float* __restrict__ h,
                                               const float* __restrict__ W,
                                               const float* __restrict__ dis,
                                               float* __restrict__ u, int n) {
    __shared__ float Ws[HID * HID];    // 4 KB
    __shared__ float xs[128 * 36];     // 18.4 KB, pitch 36
    int tid = threadIdx.x;
    for (int i = tid; i < HID * HID; i += 256) Ws[i] = W[i];
    int node0 = blockIdx.x * 128;
    int cg = tid & 7, gq = tid >> 3;
    const float4* h4g = (const float4*)h;
    for (int i = tid; i < 128 * 8; i += 256) {
        int row = i >> 3, q = i & 7;
        int node = node0 + row;
        float4 v = (node < n) ? h4g[(size_t)node * 8 + q]
                              : make_float4(0.f, 0.f, 0.f, 0.f);
        *(float4*)&xs[row * 36 + q * 4] = v;
    }
    float4 acc[4];
#pragma unroll
    for (int m = 0; m < 4; ++m) acc[m] = make_float4(0.f, 0.f, 0.f, 0.f);
    __syncthreads();
#pragma unroll
    for (int ks = 0; ks < 8; ++ks) {
        int kg = ks * 4;
        float4 w0 = *(const float4*)&Ws[(kg + 0) * HID + cg * 4];
        float4 w1 = *(const float4*)&Ws[(kg + 1) * HID + cg * 4];
        float4 w2 = *(const float4*)&Ws[(kg + 2) * HID + cg * 4];
        float4 w3 = *(const float4*)&Ws[(kg + 3) * HID + cg * 4];
#pragma unroll
        for (int m = 0; m < 4; ++m) {
            float4 xv = *(const float4*)&xs[(gq + 32 * m) * 36 + ks * 4];
            fma4(acc[m], xv.x, w0);
            fma4(acc[m], xv.y, w1);
            fma4(acc[m], xv.z, w2);
            fma4(acc[m], xv.w, w3);
        }
    }
#pragma unroll
    for (int m = 0; m < 4; ++m) {
        int node = node0 + gq + 32 * m;
        if (node < n) {
            float ds = dis[node];
            float4 r;
            r.x = acc[m].x * ds; r.y = acc[m].y * ds;
            r.z = acc[m].z * ds; r.w = acc[m].w * ds;
            *(float4*)&u[(size_t)node * HID + cg * 4] = r;
        }
    }
}

__global__ void k_dot32(const float* __restrict__ h, const float* __restrict__ W3,
                        const float* __restrict__ dis, float* __restrict__ s, int n) {
    int tid = threadIdx.x;
    int c = tid & 31, g = tid >> 5;
    int node = blockIdx.x * 8 + g;
    float v = 0.0f;
    if (node < n) v = h[(size_t)node * HID + c] * W3[c];
#pragma unroll
    for (int off = 16; off > 0; off >>= 1) v += __shfl_down(v, off, 32);
    if (node < n && c == 0) s[node] = v * dis[node];
}

// ================= gather aggregation =================

__global__ __launch_bounds__(256) void k_gather32(const float4* __restrict__ u4,
                                                  const int* __restrict__ es,
                                                  const int* __restrict__ offsets,
                                                  const float* __restrict__ dis,
                                                  const float* __restrict__ b,
                                                  float4* __restrict__ h4, int n) {
    int t = blockIdx.x * 256 + threadIdx.x;
    int node = t >> 3, q = t & 7;
    if (node >= n) return;
    int s0 = offsets[node];
    int s1 = offsets[node + 1];
    float4 acc = u4[(size_t)node * 8 + q];   // self-loop
    int ei = s0;
    for (; ei + 4 <= s1; ei += 4) {
        int e0 = es[ei], e1 = es[ei + 1], e2 = es[ei + 2], e3 = es[ei + 3];
        float4 v0 = u4[(size_t)e0 * 8 + q];
        float4 v1 = u4[(size_t)e1 * 8 + q];
        float4 v2 = u4[(size_t)e2 * 8 + q];
        float4 v3 = u4[(size_t)e3 * 8 + q];
        acc.x += (v0.x + v1.x) + (v2.x + v3.x);
        acc.y += (v0.y + v1.y) + (v2.y + v3.y);
        acc.z += (v0.z + v1.z) + (v2.z + v3.z);
        acc.w += (v0.w + v1.w) + (v2.w + v3.w);
    }
    for (; ei < s1; ++ei) {
        int s = es[ei];
        float4 v = u4[(size_t)s * 8 + q];
        acc.x += v.x; acc.y += v.y; acc.z += v.z; acc.w += v.w;
    }
    float ds = dis[node];
    float4 r;
    r.x = fmaxf(fmaf(ds, acc.x, b[q * 4 + 0]), 0.0f);
    r.y = fmaxf(fmaf(ds, acc.y, b[q * 4 + 1]), 0.0f);
    r.z = fmaxf(fmaf(ds, acc.z, b[q * 4 + 2]), 0.0f);
    r.w = fmaxf(fmaf(ds, acc.w, b[q * 4 + 3]), 0.0f);
    h4[(size_t)node * 8 + q] = r;
}

__global__ void k_gather1(const float* __restrict__ sv, const int* __restrict__ es,
                          const int* __restrict__ offsets, const float* __restrict__ dis,
                          const float* __restrict__ b3, float* __restrict__ out, int n) {
    int d = blockIdx.x * 256 + threadIdx.x;
    if (d >= n) return;
    float acc = sv[d];
    int s0 = offsets[d], s1 = offsets[d + 1];
    int ei = s0;
    for (; ei + 4 <= s1; ei += 4) {
        float v0 = sv[es[ei]], v1 = sv[es[ei + 1]];
        float v2 = sv[es[ei + 2]], v3 = sv[es[ei + 3]];
        acc += (v0 + v1) + (v2 + v3);
    }
    for (; ei < s1; ++ei) acc += sv[es[ei]];
    float z = dis[d] * acc + b3[0];
    out[d] = 1.0f / (1.0f + expf(-z));
}

// ================= launch =================

extern "C" void kernel_launch(void* const* d_in, const int* in_sizes, int n_in,
                              void* d_out, int out_size, void* d_ws, size_t ws_size,
                              hipStream_t stream) {
    const float* x  = (const float*)d_in[0];
    const int*   ei = (const int*)d_in[1];
    const float* W1 = (const float*)d_in[2];
    const float* b1 = (const float*)d_in[3];
    const float* W2 = (const float*)d_in[4];
    const float* b2 = (const float*)d_in[5];
    const float* W3 = (const float*)d_in[6];
    const float* b3 = (const float*)d_in[7];
    float* out = (float*)d_out;

    int n = out_size;             // 150000
    int e = in_sizes[1] / 2;      // 2400000
    const int* src = ei;
    const int* dst = ei + e;

    int nbuckets = (n + NPB - 1) / NPB;   // 586

    float* A        = (float*)d_ws;                 // n*32 f
    float* B        = A + (size_t)n * HID;          // n*32 f (aliases tmp during CSR build)
    float* dis      = B + (size_t)n * HID;          // n f
    float* Cs       = dis + n;                      // n f
    int*   offsets  = (int*)(Cs + n);               // n+1 i
    int*   es       = offsets + (n + 1);            // e i
    int*   bin_hist = es + e;                       // nbuckets i
    int*   bin_off  = bin_hist + nbuckets;          // nbuckets+1 i
    int*   bin_cur  = bin_off + (nbuckets + 1);     // nbuckets i
    unsigned* tmp   = (unsigned*)B;

    dim3 blk(256);
    int gN    = (n + 255) / 256;
    int g8    = (n + 7) / 8;
    int gN8   = (n * 8 + 255) / 256;
    int g128  = (n + 127) / 128;
    int gEb   = (e + EPB - 1) / EPB;

    // ---- CSR build ----
    hipMemsetAsync(bin_hist, 0, (size_t)nbuckets * sizeof(int), stream);
    k_bhist<<<gEb, blk, 0, stream>>>(dst, bin_hist, e, nbuckets);
    k_bscan<<<1, 1024, 0, stream>>>(bin_hist, bin_off, bin_cur, offsets, nbuckets, n, e);
    k_bpart<<<gEb, blk, 0, stream>>>(src, dst, bin_cur, tmp, e, nbuckets);
    k_bcsr <<<nbuckets, blk, 0, stream>>>(tmp, bin_off, es, offsets, dis, n);

    // ---- layer 1 ----
    k_gemm1   <<<g128, blk, 0, stream>>>(x, W1, dis, A, n);
    k_gather32<<<gN8,  blk, 0, stream>>>((const float4*)A, es, offsets, dis, b1, (float4*)B, n);

    // ---- layer 2 ----
    k_gemm2   <<<g128, blk, 0, stream>>>(B, W2, dis, A, n);
    k_gather32<<<gN8,  blk, 0, stream>>>((const float4*)A, es, offsets, dis, b2, (float4*)B, n);

    // ---- layer 3 ----
    k_dot32  <<<g8, blk, 0, stream>>>(B, W3, dis, Cs, n);
    k_gather1<<<gN, blk, 0, stream>>>(Cs, es, offsets, dis, b3, out, n);
}

// Round 5
// 375.327 us; speedup vs baseline: 6.4941x; 1.0834x over previous
//
#include <hip/hip_runtime.h>
#include <math.h>

#define F_IN 128
#define HID  32

#define NPB   256      // nodes per bucket (dst >> 8)
#define MAXNB 1024     // max buckets supported by the one-block scan
#define EPB   8192     // edges per block in coarse passes

__device__ __forceinline__ void fma4(float4& a, float s, const float4& w) {
    a.x = fmaf(s, w.x, a.x);
    a.y = fmaf(s, w.y, a.y);
    a.z = fmaf(s, w.z, a.z);
    a.w = fmaf(s, w.w, a.w);
}

// ================= binned CSR build =================

__global__ __launch_bounds__(256) void k_bhist(const int* __restrict__ dst,
                                               int* __restrict__ bin_hist,
                                               int e, int nbuckets) {
    __shared__ int h[MAXNB];
    int tid = threadIdx.x;
    for (int i = tid; i < nbuckets; i += 256) h[i] = 0;
    __syncthreads();
    int base = blockIdx.x * EPB;
    int end = base + EPB; if (end > e) end = e;
    for (int i = base + tid; i < end; i += 256)
        atomicAdd(&h[dst[i] >> 8], 1);
    __syncthreads();
    for (int i = tid; i < nbuckets; i += 256)
        if (h[i]) atomicAdd(&bin_hist[i], h[i]);
}

__global__ __launch_bounds__(1024) void k_bscan(const int* __restrict__ bin_hist,
                                                int* __restrict__ bin_off,
                                                int* __restrict__ bin_cur,
                                                int* __restrict__ offsets,
                                                int nbuckets, int n, int e) {
    __shared__ int sh[MAXNB];
    int t = threadIdx.x;
    int v = (t < nbuckets) ? bin_hist[t] : 0;
    sh[t] = v; __syncthreads();
    for (int off = 1; off < MAXNB; off <<= 1) {
        int a = (t >= off) ? sh[t - off] : 0;
        __syncthreads();
        sh[t] += a;
        __syncthreads();
    }
    int excl = sh[t] - v;
    if (t < nbuckets) { bin_off[t] = excl; bin_cur[t] = excl; }
    if (t == 0) { bin_off[nbuckets] = e; offsets[n] = e; }
}

__global__ __launch_bounds__(256) void k_bpart(const int* __restrict__ src,
                                               const int* __restrict__ dst,
                                               int* __restrict__ bin_cur,
                                               unsigned* __restrict__ tmp,
                                               int e, int nbuckets) {
    __shared__ int h[MAXNB];
    __shared__ int lc[MAXNB];
    int tid = threadIdx.x;
    for (int i = tid; i < nbuckets; i += 256) h[i] = 0;
    __syncthreads();
    int base = blockIdx.x * EPB;
    int end = base + EPB; if (end > e) end = e;
    for (int i = base + tid; i < end; i += 256)
        atomicAdd(&h[dst[i] >> 8], 1);
    __syncthreads();
    for (int i = tid; i < nbuckets; i += 256) {
        int c = h[i];
        h[i] = c ? atomicAdd(&bin_cur[i], c) : 0;
        lc[i] = 0;
    }
    __syncthreads();
    for (int i = base + tid; i < end; i += 256) {
        int d = dst[i];
        int b = d >> 8;
        int r = atomicAdd(&lc[b], 1);
        tmp[h[b] + r] = (unsigned)src[i] | ((unsigned)(d & (NPB - 1)) << 18);
    }
}

__global__ __launch_bounds__(256) void k_bcsr(const unsigned* __restrict__ tmp,
                                              const int* __restrict__ bin_off,
                                              int* __restrict__ es,
                                              int* __restrict__ offsets,
                                              float* __restrict__ dis, int n) {
    __shared__ int cnt[NPB];
    __shared__ int sh[NPB];
    __shared__ int cur[NPB];
    int b = blockIdx.x, t = threadIdx.x;
    cnt[t] = 0;
    __syncthreads();
    int s0 = bin_off[b], s1 = bin_off[b + 1];
    for (int i = s0 + t; i < s1; i += 256)
        atomicAdd(&cnt[(tmp[i] >> 18) & (NPB - 1)], 1);
    __syncthreads();
    int v = cnt[t];
    sh[t] = v; __syncthreads();
    for (int off = 1; off < NPB; off <<= 1) {
        int a = (t >= off) ? sh[t - off] : 0;
        __syncthreads();
        sh[t] += a;
        __syncthreads();
    }
    int excl = sh[t] - v;
    int node = b * NPB + t;
    if (node < n) {
        offsets[node] = s0 + excl;
        dis[node] = rsqrtf((float)(v + 1));
    }
    cur[t] = excl;
    __syncthreads();
    for (int i = s0 + t; i < s1; i += 256) {
        unsigned w = tmp[i];
        int dl = (w >> 18) & (NPB - 1);
        int r = atomicAdd(&cur[dl], 1);
        es[s0 + r] = (int)(w & 0x3FFFFu);
    }
}

// ================= transforms =================

// Staging-free: W in LDS (16 KB); x read directly from global (float4,
// broadcast across the 8 lanes sharing gq). 128 nodes/block.
__global__ __launch_bounds__(256) void k_gemm1(const float* __restrict__ x,
                                               const float* __restrict__ W,
                                               const float* __restrict__ dis,
                                               float* __restrict__ u, int n) {
    __shared__ float Ws[F_IN * HID];   // 16 KB only
    int tid = threadIdx.x;
    for (int i = tid; i < F_IN * HID; i += 256) Ws[i] = W[i];
    int node0 = blockIdx.x * 128;
    int cg = tid & 7, gq = tid >> 3;
    int row[4];
#pragma unroll
    for (int m = 0; m < 4; ++m) {
        int node = node0 + gq + 32 * m;
        row[m] = (node < n) ? node : 0;      // clamp: keeps loads safe & broadcast
    }
    const float4* x4 = (const float4*)x;
    float4 acc[4];
#pragma unroll
    for (int m = 0; m < 4; ++m) acc[m] = make_float4(0.f, 0.f, 0.f, 0.f);
    __syncthreads();
#pragma unroll 4
    for (int ks = 0; ks < 32; ++ks) {
        float4 xv[4];
#pragma unroll
        for (int m = 0; m < 4; ++m) xv[m] = x4[(size_t)row[m] * 32 + ks];
        float4 w0 = *(const float4*)&Ws[(ks * 4 + 0) * HID + cg * 4];
        float4 w1 = *(const float4*)&Ws[(ks * 4 + 1) * HID + cg * 4];
        float4 w2 = *(const float4*)&Ws[(ks * 4 + 2) * HID + cg * 4];
        float4 w3 = *(const float4*)&Ws[(ks * 4 + 3) * HID + cg * 4];
#pragma unroll
        for (int m = 0; m < 4; ++m) {
            fma4(acc[m], xv[m].x, w0);
            fma4(acc[m], xv[m].y, w1);
            fma4(acc[m], xv[m].z, w2);
            fma4(acc[m], xv[m].w, w3);
        }
    }
#pragma unroll
    for (int m = 0; m < 4; ++m) {
        int node = node0 + gq + 32 * m;
        if (node < n) {
            float ds = dis[node];
            float4 r;
            r.x = acc[m].x * ds; r.y = acc[m].y * ds;
            r.z = acc[m].z * ds; r.w = acc[m].w * ds;
            *(float4*)&u[(size_t)node * HID + cg * 4] = r;
        }
    }
}

// K=32 variant, same structure (4 KB LDS).
__global__ __launch_bounds__(256) void k_gemm2(const float* __restrict__ h,
                                               const float* __restrict__ W,
                                               const float* __restrict__ dis,
                                               float* __restrict__ u, int n) {
    __shared__ float Ws[HID * HID];    // 4 KB
    int tid = threadIdx.x;
    for (int i = tid; i < HID * HID; i += 256) Ws[i] = W[i];
    int node0 = blockIdx.x * 128;
    int cg = tid & 7, gq = tid >> 3;
    int row[4];
#pragma unroll
    for (int m = 0; m < 4; ++m) {
        int node = node0 + gq + 32 * m;
        row[m] = (node < n) ? node : 0;
    }
    const float4* h4 = (const float4*)h;
    float4 acc[4];
#pragma unroll
    for (int m = 0; m < 4; ++m) acc[m] = make_float4(0.f, 0.f, 0.f, 0.f);
    __syncthreads();
#pragma unroll
    for (int ks = 0; ks < 8; ++ks) {
        float4 xv[4];
#pragma unroll
        for (int m = 0; m < 4; ++m) xv[m] = h4[(size_t)row[m] * 8 + ks];
        float4 w0 = *(const float4*)&Ws[(ks * 4 + 0) * HID + cg * 4];
        float4 w1 = *(const float4*)&Ws[(ks * 4 + 1) * HID + cg * 4];
        float4 w2 = *(const float4*)&Ws[(ks * 4 + 2) * HID + cg * 4];
        float4 w3 = *(const float4*)&Ws[(ks * 4 + 3) * HID + cg * 4];
#pragma unroll
        for (int m = 0; m < 4; ++m) {
            fma4(acc[m], xv[m].x, w0);
            fma4(acc[m], xv[m].y, w1);
            fma4(acc[m], xv[m].z, w2);
            fma4(acc[m], xv[m].w, w3);
        }
    }
#pragma unroll
    for (int m = 0; m < 4; ++m) {
        int node = node0 + gq + 32 * m;
        if (node < n) {
            float ds = dis[node];
            float4 r;
            r.x = acc[m].x * ds; r.y = acc[m].y * ds;
            r.z = acc[m].z * ds; r.w = acc[m].w * ds;
            *(float4*)&u[(size_t)node * HID + cg * 4] = r;
        }
    }
}

// ================= gather aggregation =================

__global__ __launch_bounds__(256) void k_gather32(const float4* __restrict__ u4,
                                                  const int* __restrict__ es,
                                                  const int* __restrict__ offsets,
                                                  const float* __restrict__ dis,
                                                  const float* __restrict__ b,
                                                  float4* __restrict__ h4, int n) {
    int t = blockIdx.x * 256 + threadIdx.x;
    int node = t >> 3, q = t & 7;
    if (node >= n) return;
    int s0 = offsets[node];
    int s1 = offsets[node + 1];
    float4 acc = u4[(size_t)node * 8 + q];   // self-loop
    int ei = s0;
    for (; ei + 4 <= s1; ei += 4) {
        int e0 = es[ei], e1 = es[ei + 1], e2 = es[ei + 2], e3 = es[ei + 3];
        float4 v0 = u4[(size_t)e0 * 8 + q];
        float4 v1 = u4[(size_t)e1 * 8 + q];
        float4 v2 = u4[(size_t)e2 * 8 + q];
        float4 v3 = u4[(size_t)e3 * 8 + q];
        acc.x += (v0.x + v1.x) + (v2.x + v3.x);
        acc.y += (v0.y + v1.y) + (v2.y + v3.y);
        acc.z += (v0.z + v1.z) + (v2.z + v3.z);
        acc.w += (v0.w + v1.w) + (v2.w + v3.w);
    }
    for (; ei < s1; ++ei) {
        int s = es[ei];
        float4 v = u4[(size_t)s * 8 + q];
        acc.x += v.x; acc.y += v.y; acc.z += v.z; acc.w += v.w;
    }
    float ds = dis[node];
    float4 r;
    r.x = fmaxf(fmaf(ds, acc.x, b[q * 4 + 0]), 0.0f);
    r.y = fmaxf(fmaf(ds, acc.y, b[q * 4 + 1]), 0.0f);
    r.z = fmaxf(fmaf(ds, acc.z, b[q * 4 + 2]), 0.0f);
    r.w = fmaxf(fmaf(ds, acc.w, b[q * 4 + 3]), 0.0f);
    h4[(size_t)node * 8 + q] = r;
}

// Layer-2 gather with fused W3 dot: s[node] = dis * (relu(...)·W3).
// h2 is never materialized.
__global__ __launch_bounds__(256) void k_gather32_dot(const float4* __restrict__ u4,
                                                      const int* __restrict__ es,
                                                      const int* __restrict__ offsets,
                                                      const float* __restrict__ dis,
                                                      const float* __restrict__ b,
                                                      const float* __restrict__ W3,
                                                      float* __restrict__ s, int n) {
    int t = blockIdx.x * 256 + threadIdx.x;
    int node = t >> 3, q = t & 7;
    if (node >= n) return;
    int s0 = offsets[node];
    int s1 = offsets[node + 1];
    float4 acc = u4[(size_t)node * 8 + q];
    int ei = s0;
    for (; ei + 4 <= s1; ei += 4) {
        int e0 = es[ei], e1 = es[ei + 1], e2 = es[ei + 2], e3 = es[ei + 3];
        float4 v0 = u4[(size_t)e0 * 8 + q];
        float4 v1 = u4[(size_t)e1 * 8 + q];
        float4 v2 = u4[(size_t)e2 * 8 + q];
        float4 v3 = u4[(size_t)e3 * 8 + q];
        acc.x += (v0.x + v1.x) + (v2.x + v3.x);
        acc.y += (v0.y + v1.y) + (v2.y + v3.y);
        acc.z += (v0.z + v1.z) + (v2.z + v3.z);
        acc.w += (v0.w + v1.w) + (v2.w + v3.w);
    }
    for (; ei < s1; ++ei) {
        int sc = es[ei];
        float4 v = u4[(size_t)sc * 8 + q];
        acc.x += v.x; acc.y += v.y; acc.z += v.z; acc.w += v.w;
    }
    float ds = dis[node];
    float4 r;
    r.x = fmaxf(fmaf(ds, acc.x, b[q * 4 + 0]), 0.0f);
    r.y = fmaxf(fmaf(ds, acc.y, b[q * 4 + 1]), 0.0f);
    r.z = fmaxf(fmaf(ds, acc.z, b[q * 4 + 2]), 0.0f);
    r.w = fmaxf(fmaf(ds, acc.w, b[q * 4 + 3]), 0.0f);
    float p = r.x * W3[q * 4 + 0] + r.y * W3[q * 4 + 1]
            + r.z * W3[q * 4 + 2] + r.w * W3[q * 4 + 3];
    p += __shfl_down(p, 4, 8);
    p += __shfl_down(p, 2, 8);
    p += __shfl_down(p, 1, 8);
    if (q == 0) s[node] = p * ds;
}

__global__ void k_gather1(const float* __restrict__ sv, const int* __restrict__ es,
                          const int* __restrict__ offsets, const float* __restrict__ dis,
                          const float* __restrict__ b3, float* __restrict__ out, int n) {
    int d = blockIdx.x * 256 + threadIdx.x;
    if (d >= n) return;
    float acc = sv[d];
    int s0 = offsets[d], s1 = offsets[d + 1];
    int ei = s0;
    for (; ei + 4 <= s1; ei += 4) {
        float v0 = sv[es[ei]], v1 = sv[es[ei + 1]];
        float v2 = sv[es[ei + 2]], v3 = sv[es[ei + 3]];
        acc += (v0 + v1) + (v2 + v3);
    }
    for (; ei < s1; ++ei) acc += sv[es[ei]];
    float z = dis[d] * acc + b3[0];
    out[d] = 1.0f / (1.0f + expf(-z));
}

// ================= launch =================

extern "C" void kernel_launch(void* const* d_in, const int* in_sizes, int n_in,
                              void* d_out, int out_size, void* d_ws, size_t ws_size,
                              hipStream_t stream) {
    const float* x  = (const float*)d_in[0];
    const int*   ei = (const int*)d_in[1];
    const float* W1 = (const float*)d_in[2];
    const float* b1 = (const float*)d_in[3];
    const float* W2 = (const float*)d_in[4];
    const float* b2 = (const float*)d_in[5];
    const float* W3 = (const float*)d_in[6];
    const float* b3 = (const float*)d_in[7];
    float* out = (float*)d_out;

    int n = out_size;             // 150000
    int e = in_sizes[1] / 2;      // 2400000
    const int* src = ei;
    const int* dst = ei + e;

    int nbuckets = (n + NPB - 1) / NPB;   // 586

    float* A        = (float*)d_ws;                 // n*32 f
    float* B        = A + (size_t)n * HID;          // n*32 f (aliases tmp during CSR build)
    float* dis      = B + (size_t)n * HID;          // n f
    float* Cs       = dis + n;                      // n f
    int*   offsets  = (int*)(Cs + n);               // n+1 i
    int*   es       = offsets + (n + 1);            // e i
    int*   bin_hist = es + e;                       // nbuckets i
    int*   bin_off  = bin_hist + nbuckets;          // nbuckets+1 i
    int*   bin_cur  = bin_off + (nbuckets + 1);     // nbuckets i
    unsigned* tmp   = (unsigned*)B;

    dim3 blk(256);
    int gN    = (n + 255) / 256;
    int gN8   = (n * 8 + 255) / 256;
    int g128  = (n + 127) / 128;
    int gEb   = (e + EPB - 1) / EPB;

    // ---- CSR build ----
    hipMemsetAsync(bin_hist, 0, (size_t)nbuckets * sizeof(int), stream);
    k_bhist<<<gEb, blk, 0, stream>>>(dst, bin_hist, e, nbuckets);
    k_bscan<<<1, 1024, 0, stream>>>(bin_hist, bin_off, bin_cur, offsets, nbuckets, n, e);
    k_bpart<<<gEb, blk, 0, stream>>>(src, dst, bin_cur, tmp, e, nbuckets);
    k_bcsr <<<nbuckets, blk, 0, stream>>>(tmp, bin_off, es, offsets, dis, n);

    // ---- layer 1 ----
    k_gemm1   <<<g128, blk, 0, stream>>>(x, W1, dis, A, n);
    k_gather32<<<gN8,  blk, 0, stream>>>((const float4*)A, es, offsets, dis, b1, (float4*)B, n);

    // ---- layer 2 (+ fused layer-3 transform) ----
    k_gemm2       <<<g128, blk, 0, stream>>>(B, W2, dis, A, n);
    k_gather32_dot<<<gN8,  blk, 0, stream>>>((const float4*)A, es, offsets, dis, b2, W3, Cs, n);

    // ---- layer 3 aggregation ----
    k_gather1<<<gN, blk, 0, stream>>>(Cs, es, offsets, dis, b3, out, n);
}